// Round 15
// baseline (181.362 us; speedup 1.0000x reference)
//
#include <hip/hip_runtime.h>
#include <hip/hip_bf16.h>
#include <math.h>

// ---------- types ----------
typedef __bf16 bf16x8 __attribute__((ext_vector_type(8)));
typedef float  floatx4 __attribute__((ext_vector_type(4)));
typedef float  floatx16 __attribute__((ext_vector_type(16)));
typedef unsigned u32x2 __attribute__((ext_vector_type(2)));

#define MFMA(a, b, c)   __builtin_amdgcn_mfma_f32_16x16x32_bf16((a), (b), (c), 0, 0, 0)
#define MFMA32(a, b, c) __builtin_amdgcn_mfma_f32_32x32x16_bf16((a), (b), (c), 0, 0, 0)

__device__ __forceinline__ unsigned short f2bf(float f) {
  union { float f; unsigned u; } v; v.f = f;
  unsigned r = v.u + 0x7FFFu + ((v.u >> 16) & 1u);
  return (unsigned short)(r >> 16);
}
__device__ __forceinline__ float bf2f(unsigned short u) {
  union { unsigned u; float f; } v; v.u = ((unsigned)u) << 16;
  return v.f;
}
// pack two f32 -> one dword of 2 bf16 (RNE); compiler emits v_cvt_pk_bf16_f32
__device__ __forceinline__ unsigned pack2(float a, float b) {
  __bf16 x = (__bf16)a, y = (__bf16)b;
  unsigned short ux = __builtin_bit_cast(unsigned short, x);
  unsigned short uy = __builtin_bit_cast(unsigned short, y);
  return (unsigned)ux | ((unsigned)uy << 16);
}
__device__ __forceinline__ float exp2_fast(float x) {
#if __has_builtin(__builtin_amdgcn_exp2f)
  return __builtin_amdgcn_exp2f(x);
#else
  return exp2f(x);
#endif
}

// B=4, C=256, N=4096, Ci=32, SPLITS=4
// ---------- K_wconv: Wall[320][256] bf16 = [Wq;Wk;Wv] ----------
__global__ __launch_bounds__(256) void k_wconv(const float* __restrict__ Wq,
                                               const float* __restrict__ Wk,
                                               const float* __restrict__ Wv,
                                               unsigned short* __restrict__ Wall) {
  int i = blockIdx.x * 256 + threadIdx.x;
  int o = i >> 8, c = i & 255;
  float v = (o < 32) ? Wq[o * 256 + c]
          : (o < 64) ? Wk[(o - 32) * 256 + c]
                     : Wv[(o - 64) * 256 + c];
  Wall[i] = f2bf(v);
}

// ---------- K_projx v2 (round-14, verbatim): coalesced x reads. 512 blocks x 4 waves ----
// Outputs (fragment-linear for k_attn):
//   qbf[b][qblk128][kh2][hi2][q32][8ch]   (q pre-scaled by log2e, bias folded)
//   kbf[b][tile128][kh2][hi2][key32][8ch]
//   vbf[b][kb128][cb8][kk2][hi2][ch32][8key]
__global__ __launch_bounds__(256) void k_projx(const float* __restrict__ x,
                                               const unsigned short* __restrict__ Wall,
                                               const float* __restrict__ bq,
                                               const float* __restrict__ bk,
                                               const float* __restrict__ bv,
                                               unsigned short* __restrict__ qbf,
                                               unsigned short* __restrict__ kbf,
                                               unsigned short* __restrict__ vbf) {
  int b = blockIdx.x >> 7;
  int nb = blockIdx.x & 127;
  int n0 = nb * 32;
  int tid = threadIdx.x;
  int qr = tid >> 6;                // wave id = output quarter
  int lane = tid & 63;
  int l15 = lane & 15, quad = lane >> 4;

  __shared__ alignas(16) unsigned short xs[32][264];
  __shared__ alignas(16) unsigned short Os[4][64][24];

  {
    int g = tid & 7;
    int r0 = tid >> 3;              // 0..31
    const float* xcol = x + (size_t)b * 256 * 4096 + n0 + g * 4;
#pragma unroll
    for (int pass = 0; pass < 8; ++pass) {
      int r = pass * 32 + r0;       // channel 0..255
      float4 d = *(const float4*)(xcol + (size_t)r * 4096);
      xs[g * 4 + 0][r] = f2bf(d.x);
      xs[g * 4 + 1][r] = f2bf(d.y);
      xs[g * 4 + 2][r] = f2bf(d.z);
      xs[g * 4 + 3][r] = f2bf(d.w);
    }
  }
  __syncthreads();

#pragma unroll
  for (int ms = 0; ms < 2; ++ms) {
    int m0 = n0 + ms * 16;

    floatx4 acc[5];
#pragma unroll
    for (int tt = 0; tt < 5; ++tt) acc[tt] = floatx4{0.f, 0.f, 0.f, 0.f};

#pragma unroll
    for (int ks = 0; ks < 8; ++ks) {
      bf16x8 a = *(const bf16x8*)&xs[ms * 16 + l15][ks * 32 + quad * 8];
      {
        bf16x8 w = *(const bf16x8*)(Wall + (size_t)(qr * 16 + l15) * 256 + ks * 32 + quad * 8);
        acc[0] = MFMA(a, w, acc[0]);
      }
#pragma unroll
      for (int t = 0; t < 4; ++t) {
        int gt = 4 + qr * 4 + t;
        bf16x8 w = *(const bf16x8*)(Wall + (size_t)(gt * 16 + l15) * 256 + ks * 32 + quad * 8);
        acc[1 + t] = MFMA(a, w, acc[1 + t]);
      }
    }
    {
      int o = qr * 16 + l15;
      float bias = (o < 32) ? bq[o] : bk[o - 32];
      float scale = (o < 32) ? 1.44269504088896340736f : 1.0f;
      unsigned short* dst = (o < 32) ? qbf : kbf;
      int oc = o & 31;
      int kh = oc >> 4, h2 = (oc >> 3) & 1, c8 = oc & 7;
#pragma unroll
      for (int r = 0; r < 4; ++r) {
        int m = m0 + quad * 4 + r;
        dst[(size_t)b * 131072 + (size_t)(m >> 5) * 1024 + kh * 512 + h2 * 256 +
            (m & 31) * 8 + c8] = f2bf((acc[0][r] + bias) * scale);
      }
    }
#pragma unroll
    for (int t = 0; t < 4; ++t) {
      int lr = t * 16 + l15;                  // local channel 0..63
      int c = qr * 64 + lr;                   // global v channel
      float bias = bv[c];
#pragma unroll
      for (int r = 0; r < 4; ++r)
        Os[qr][lr][quad * 4 + r] = f2bf(acc[1 + t][r] + bias);
    }
    {
      int kb = nb, kk = ms;
#pragma unroll
      for (int i = 0; i < 2; ++i) {
        int idx = lane + 64 * i;
        int r = idx >> 1, g = idx & 1;
        int c = qr * 64 + r;
        int cb = c >> 5, ch = c & 31;
        *(uint4*)(vbf + (size_t)b * 1048576 + (size_t)kb * 8192 +
                  (size_t)cb * 1024 + kk * 512 + g * 256 + ch * 8) =
            *(const uint4*)&Os[qr][r][g * 8];
      }
    }
  }
}

// ---------- softmax helper (unchanged, verified) ----------
__device__ __forceinline__ void softmax_pack(floatx16 st, float& lp, bf16x8 (&pa)[2], int hi) {
  float p[16];
#pragma unroll
  for (int r = 0; r < 16; ++r) p[r] = exp2_fast(st[r]);
  lp += (((p[0] + p[1]) + (p[2] + p[3])) + ((p[4] + p[5]) + (p[6] + p[7]))) +
        (((p[8] + p[9]) + (p[10] + p[11])) + ((p[12] + p[13]) + (p[14] + p[15])));
  unsigned d0[4], d1[4];
#pragma unroll
  for (int t = 0; t < 4; ++t) {
    d0[t] = pack2(p[4 * t + 0], p[4 * t + 1]);
    d1[t] = pack2(p[4 * t + 2], p[4 * t + 3]);
  }
#pragma unroll
  for (int ks = 0; ks < 2; ++ks) {
#if __has_builtin(__builtin_amdgcn_permlane32_swap)
    (void)hi;
    u32x2 r0 = __builtin_amdgcn_permlane32_swap(d0[2 * ks], d0[2 * ks + 1], false, false);
    u32x2 r1 = __builtin_amdgcn_permlane32_swap(d1[2 * ks], d1[2 * ks + 1], false, false);
    union { unsigned u[4]; bf16x8 v; } u;
    u.u[0] = r0[0]; u.u[1] = r1[0]; u.u[2] = r0[1]; u.u[3] = r1[1];
    pa[ks] = u.v;
#else
    unsigned s0 = hi ? d0[2 * ks] : d0[2 * ks + 1];
    unsigned s1 = hi ? d1[2 * ks] : d1[2 * ks + 1];
    unsigned o0 = (unsigned)__shfl_xor((int)s0, 32);
    unsigned o1 = (unsigned)__shfl_xor((int)s1, 32);
    union { unsigned u[4]; bf16x8 v; } u;
    u.u[0] = hi ? o0 : d0[2 * ks];
    u.u[1] = hi ? o1 : d1[2 * ks];
    u.u[2] = hi ? d0[2 * ks + 1] : o0;
    u.u[3] = hi ? d1[2 * ks + 1] : o1;
    pa[ks] = u.v;
#endif
  }
}

// ---------- K_attn v11: 128q x 64ch waves (half the V line-traffic per query) ----------
// Wave = (split s) x 128 queries x 64 channels. V loads: 4/iter (vs 10 total loads
// in v9's 64qx128ch) -> L1 line transactions per CU per iter 1280 -> 768.
// Q tile (8KB) staged in LDS, shared by all 4 waves; read per-iter as ds_read_b128
// (keeps arch VGPRs ~96 + 128 acc = 224 <= 256, no spill). Fused v9-style epilogue
// extended to 128q; Ol aliases the Q buffer after a barrier (72KB LDS, 2 blk/CU).
// grid = 512 = b(4) x cz(4) x qb(32); XCD-swizzled.
__global__ __launch_bounds__(256, 2) void k_attn(const unsigned short* __restrict__ qbf,
                                                 const unsigned short* __restrict__ kbf,
                                                 const unsigned short* __restrict__ vbf,
                                                 const float* __restrict__ x,
                                                 const float* __restrict__ gma,
                                                 float* __restrict__ out) {
  // XCD swizzle: nwg=512, 8 XCDs -> XCD x owns decoded range [x*64, x*64+64)
  int wg = (blockIdx.x & 7) * 64 + (blockIdx.x >> 3);
  const int qb = wg & 31;                   // 128-query tile
  const int g  = wg >> 5;                   // 0..15 = b(4) x cz(4)
  const int cz = g & 3;                     // 64-channel quarter
  const int b  = g >> 2;
  const int tid = threadIdx.x;
  const int s  = tid >> 6;                  // wave id = key-split
  const int lane = tid & 63;
  const int l31 = lane & 31;
  const int hi  = lane >> 5;
  const int q0  = qb * 128;

  // SH: first 4096 shorts = Q tile [4 qtiles][1024] during main loop;
  // after the post-loop barrier, re-used as Ol[4 split][64 ch][136 q-padded].
  __shared__ alignas(16) unsigned short SH[4 * 64 * 136];
  __shared__ float lpL[4][128];
  __shared__ float ltot[128];

  const floatx16 z16 = {0.f, 0.f, 0.f, 0.f, 0.f, 0.f, 0.f, 0.f,
                        0.f, 0.f, 0.f, 0.f, 0.f, 0.f, 0.f, 0.f};

  // ---- stage Q tile -> LDS (4096 shorts, fully coalesced) ----
  {
    const unsigned short* qsrc = qbf + (size_t)b * 131072 + (size_t)(qb * 4) * 1024;
    *(uint4*)&SH[tid * 16 + 0] = *(const uint4*)(qsrc + tid * 16 + 0);
    *(uint4*)&SH[tid * 16 + 8] = *(const uint4*)(qsrc + tid * 16 + 8);
  }
  __syncthreads();

  floatx16 acc[4][2];
#pragma unroll
  for (int i = 0; i < 4; ++i)
#pragma unroll
    for (int j = 0; j < 2; ++j) acc[i][j] = z16;

  float lpq[4] = {0.f, 0.f, 0.f, 0.f};

  // K fragment base (A-operand: row = key l31, ch = kh*16 + hi*8 + j)
  const unsigned short* krow =
      kbf + (size_t)b * 131072 + (size_t)(s * 32) * 1024 + hi * 256 + l31 * 8;
  // V fragment base (B-operand: col = channel l31, key = kk*16 + hi*8 + j);
  // this wave's channels = cz*64 .. cz*64+63 (cb = cz*2, cz*2+1)
  const unsigned short* vrow =
      vbf + (size_t)b * 1048576 + (size_t)(s * 32) * 8192 + (size_t)(cz * 2) * 1024 +
      hi * 256 + l31 * 8;

  bf16x8 kf0 = *(const bf16x8*)krow;
  bf16x8 kf1 = *(const bf16x8*)(krow + 512);
  const int qoffL = hi * 256 + l31 * 8;     // per-lane Q fragment offset within a tile

  for (int it = 0; it < 32; ++it) {
    // ---- V loads (4 x 1KB contiguous): consumed at PV; ST+softmax cover latency
    bf16x8 vb[2][2];
    const unsigned short* vit = vrow + (size_t)it * 8192;
#pragma unroll
    for (int ct = 0; ct < 2; ++ct) {
      vb[ct][0] = *(const bf16x8*)(vit + ct * 1024);
      vb[ct][1] = *(const bf16x8*)(vit + ct * 1024 + 512);
    }

    // ---- per q-subtile: Q from LDS -> ST -> in-register softmax ----
    bf16x8 pa[4][2];
#pragma unroll
    for (int qs = 0; qs < 4; ++qs) {
      bf16x8 q0f = *(const bf16x8*)&SH[qs * 1024 + qoffL];
      bf16x8 q1f = *(const bf16x8*)&SH[qs * 1024 + 512 + qoffL];
      floatx16 st = MFMA32(kf0, q0f, z16);
      st = MFMA32(kf1, q1f, st);
      softmax_pack(st, lpq[qs], pa[qs], hi);
    }

    // ---- K prefetch for next iter (wrapped index keeps the last dead load in-region)
    const unsigned short* kn = krow + (size_t)((it + 1) & 31) * 1024;
    kf0 = *(const bf16x8*)kn;
    kf1 = *(const bf16x8*)(kn + 512);

    // ---- PV: 16 MFMAs; each V fragment feeds all 4 q-subtiles ----
    __builtin_amdgcn_s_setprio(1);
#pragma unroll
    for (int qs = 0; qs < 4; ++qs)
#pragma unroll
      for (int ct = 0; ct < 2; ++ct) {
        acc[qs][ct] = MFMA32(pa[qs][0], vb[ct][0], acc[qs][ct]);
        acc[qs][ct] = MFMA32(pa[qs][1], vb[ct][1], acc[qs][ct]);
      }
    __builtin_amdgcn_s_setprio(0);
  }

  // ---- fused cross-split reduction + normalize + residual epilogue ----
#pragma unroll
  for (int qs = 0; qs < 4; ++qs) {
    lpq[qs] += __shfl_xor(lpq[qs], 32);
    if (hi == 0) lpL[s][qs * 32 + l31] = lpq[qs];
  }
  __syncthreads();   // all Q reads done (SH alias now safe); lpL complete

  // Ol writes: Ol[s][ch 64][q 128 (pad 136)], aliased onto SH.
  // acc[qs][ct] reg r: query qs*32 + (r&3)+8*(r>>2)+4*hi, channel ct*32+l31.
#pragma unroll
  for (int qs = 0; qs < 4; ++qs)
#pragma unroll
    for (int ct = 0; ct < 2; ++ct)
#pragma unroll
      for (int gi = 0; gi < 4; ++gi) {
        unsigned w0 = pack2(acc[qs][ct][4 * gi + 0], acc[qs][ct][4 * gi + 1]);
        unsigned w1 = pack2(acc[qs][ct][4 * gi + 2], acc[qs][ct][4 * gi + 3]);
        unsigned long long w = (unsigned long long)w0 | ((unsigned long long)w1 << 32);
        *(unsigned long long*)&SH[((size_t)(s * 64) + ct * 32 + l31) * 136 +
                                  qs * 32 + 8 * gi + 4 * hi] = w;
      }
  if (tid < 128)
    ltot[tid] = (lpL[0][tid] + lpL[1][tid]) + (lpL[2][tid] + lpL[3][tid]);
  __syncthreads();   // Ol + ltot ready

  // merge: thread t -> ch = t>>2 (0..63), qg = t&3 (32 queries each, 128B contiguous)
  {
    const float gv = gma[0];
    int ch = tid >> 2;
    int qg = tid & 3;
    float o[32];
#pragma unroll
    for (int j = 0; j < 32; ++j) o[j] = 0.f;
#pragma unroll
    for (int sp = 0; sp < 4; ++sp) {
      const unsigned short* prow = &SH[((size_t)(sp * 64) + ch) * 136 + qg * 32];
#pragma unroll
      for (int u = 0; u < 4; ++u) {
        uint4 a = *(const uint4*)(prow + u * 8);
        unsigned uu[4] = {a.x, a.y, a.z, a.w};
#pragma unroll
        for (int jj = 0; jj < 4; ++jj) {
          o[u * 8 + 2 * jj + 0] += bf2f((unsigned short)(uu[jj] & 0xffffu));
          o[u * 8 + 2 * jj + 1] += bf2f((unsigned short)(uu[jj] >> 16));
        }
      }
    }
    size_t rowa = ((size_t)b * 256 + cz * 64 + ch) * 4096 + q0 + qg * 32;
    const float* xrow = x + rowa;
    float* orow = out + rowa;
#pragma unroll
    for (int j4 = 0; j4 < 8; ++j4) {
      float4 xv = *(const float4*)(xrow + j4 * 4);
      float4 r;
      r.x = xv.x + gv * o[j4 * 4 + 0] / ltot[qg * 32 + j4 * 4 + 0];
      r.y = xv.y + gv * o[j4 * 4 + 1] / ltot[qg * 32 + j4 * 4 + 1];
      r.z = xv.z + gv * o[j4 * 4 + 2] / ltot[qg * 32 + j4 * 4 + 2];
      r.w = xv.w + gv * o[j4 * 4 + 3] / ltot[qg * 32 + j4 * 4 + 3];
      *(float4*)(orow + j4 * 4) = r;
    }
  }
}

// ---------- launch ----------
extern "C" void kernel_launch(void* const* d_in, const int* in_sizes, int n_in,
                              void* d_out, int out_size, void* d_ws, size_t ws_size,
                              hipStream_t stream) {
  const float* x   = (const float*)d_in[0];
  const float* Wq  = (const float*)d_in[1];
  const float* bq  = (const float*)d_in[2];
  const float* Wk  = (const float*)d_in[3];
  const float* bk  = (const float*)d_in[4];
  const float* Wv  = (const float*)d_in[5];
  const float* bv  = (const float*)d_in[6];
  const float* gma = (const float*)d_in[7];
  float* out = (float*)d_out;

  // layout: [qbf][kbf][vbf][Wall]
  unsigned short* qbf  = (unsigned short*)d_ws;              // [4][128][2][2][32][8]
  unsigned short* kbf  = qbf + (size_t)4 * 131072;           // [4][128][2][2][32][8]
  unsigned short* vbf  = kbf + (size_t)4 * 131072;           // [4][128][8][2][2][32][8]
  unsigned short* Wall = vbf + (size_t)4 * 1048576;          // [320][256]

  k_wconv<<<320, 256, 0, stream>>>(Wq, Wk, Wv, Wall);
  k_projx<<<512, 256, 0, stream>>>(x, Wall, bq, bk, bv, qbf, kbf, vbf);
  k_attn<<<512, 256, 0, stream>>>(qbf, kbf, vbf, x, gma, out);
}

// Round 16
// 155.997 us; speedup vs baseline: 1.1626x; 1.1626x over previous
//
#include <hip/hip_runtime.h>
#include <hip/hip_bf16.h>
#include <math.h>

// ---------- types ----------
typedef __bf16 bf16x8 __attribute__((ext_vector_type(8)));
typedef float  floatx4 __attribute__((ext_vector_type(4)));
typedef float  floatx16 __attribute__((ext_vector_type(16)));
typedef unsigned u32x2 __attribute__((ext_vector_type(2)));

#define MFMA(a, b, c)   __builtin_amdgcn_mfma_f32_16x16x32_bf16((a), (b), (c), 0, 0, 0)
#define MFMA32(a, b, c) __builtin_amdgcn_mfma_f32_32x32x16_bf16((a), (b), (c), 0, 0, 0)

__device__ __forceinline__ unsigned short f2bf(float f) {
  union { float f; unsigned u; } v; v.f = f;
  unsigned r = v.u + 0x7FFFu + ((v.u >> 16) & 1u);
  return (unsigned short)(r >> 16);
}
__device__ __forceinline__ float bf2f(unsigned short u) {
  union { unsigned u; float f; } v; v.u = ((unsigned)u) << 16;
  return v.f;
}
// pack two f32 -> one dword of 2 bf16 (RNE); compiler emits v_cvt_pk_bf16_f32
__device__ __forceinline__ unsigned pack2(float a, float b) {
  __bf16 x = (__bf16)a, y = (__bf16)b;
  unsigned short ux = __builtin_bit_cast(unsigned short, x);
  unsigned short uy = __builtin_bit_cast(unsigned short, y);
  return (unsigned)ux | ((unsigned)uy << 16);
}
__device__ __forceinline__ float exp2_fast(float x) {
#if __has_builtin(__builtin_amdgcn_exp2f)
  return __builtin_amdgcn_exp2f(x);
#else
  return exp2f(x);
#endif
}

// B=4, C=256, N=4096, Ci=32, SPLITS=4
// ---------- K_wconv: Wall[320][256] bf16 = [Wq;Wk;Wv] ----------
__global__ __launch_bounds__(256) void k_wconv(const float* __restrict__ Wq,
                                               const float* __restrict__ Wk,
                                               const float* __restrict__ Wv,
                                               unsigned short* __restrict__ Wall) {
  int i = blockIdx.x * 256 + threadIdx.x;
  int o = i >> 8, c = i & 255;
  float v = (o < 32) ? Wq[o * 256 + c]
          : (o < 64) ? Wk[(o - 32) * 256 + c]
                     : Wv[(o - 64) * 256 + c];
  Wall[i] = f2bf(v);
}

// ---------- K_projx v4: 16-n tiles, 1024 blocks (2x TLP, half the serial passes) ----
// Block (b, nt): reads x[b][0..255][m0..m0+15] fp32 in 4 coalesced passes
// (thread = (row r0 = tid>>2, group g = tid&3); wave = 16 rows x 64B), converts to
// bf16 in LDS xs[16][264]; wave qr computes its quarter (1 qk tile + 4 v tiles).
// Outputs (fragment-linear for k_attn, identical layouts to previous rounds):
//   qbf[b][qblk128][kh2][hi2][q32][8ch]   (q pre-scaled by log2e, bias folded)
//   kbf[b][tile128][kh2][hi2][key32][8ch]
//   vbf[b][kb128][cb8][kk2][hi2][ch32][8key]
__global__ __launch_bounds__(256) void k_projx(const float* __restrict__ x,
                                               const unsigned short* __restrict__ Wall,
                                               const float* __restrict__ bq,
                                               const float* __restrict__ bk,
                                               const float* __restrict__ bv,
                                               unsigned short* __restrict__ qbf,
                                               unsigned short* __restrict__ kbf,
                                               unsigned short* __restrict__ vbf) {
  int b = blockIdx.x >> 8;
  int nt = blockIdx.x & 255;        // 16-n tile index
  int m0 = nt * 16;
  int tid = threadIdx.x;
  int qr = tid >> 6;                // wave id = output quarter
  int lane = tid & 63;
  int l15 = lane & 15, quad = lane >> 4;

  __shared__ alignas(16) unsigned short xs[16][264];
  __shared__ alignas(16) unsigned short Os[4][64][24];

  // ---- stage x -> LDS, coalesced: thread (r0 = tid>>2, g = tid&3) reads
  //      row (pass*64 + r0), cols m0 + g*4 .. +3. 4 passes cover 256 channels.
  {
    int g = tid & 3;
    int r0 = tid >> 2;              // 0..63
    const float* xcol = x + (size_t)b * 256 * 4096 + m0 + g * 4;
#pragma unroll
    for (int pass = 0; pass < 4; ++pass) {
      int r = pass * 64 + r0;       // channel 0..255
      float4 d = *(const float4*)(xcol + (size_t)r * 4096);
      xs[g * 4 + 0][r] = f2bf(d.x);
      xs[g * 4 + 1][r] = f2bf(d.y);
      xs[g * 4 + 2][r] = f2bf(d.z);
      xs[g * 4 + 3][r] = f2bf(d.w);
    }
  }
  __syncthreads();

  // ---- MFMA: 8 ks-steps x (1 qk tile + 4 v tiles) for this wave's quarter ----
  floatx4 acc[5];
#pragma unroll
  for (int tt = 0; tt < 5; ++tt) acc[tt] = floatx4{0.f, 0.f, 0.f, 0.f};

#pragma unroll
  for (int ks = 0; ks < 8; ++ks) {
    bf16x8 a = *(const bf16x8*)&xs[l15][ks * 32 + quad * 8];
    {
      bf16x8 w = *(const bf16x8*)(Wall + (size_t)(qr * 16 + l15) * 256 + ks * 32 + quad * 8);
      acc[0] = MFMA(a, w, acc[0]);
    }
#pragma unroll
    for (int t = 0; t < 4; ++t) {
      int gt = 4 + qr * 4 + t;
      bf16x8 w = *(const bf16x8*)(Wall + (size_t)(gt * 16 + l15) * 256 + ks * 32 + quad * 8);
      acc[1 + t] = MFMA(a, w, acc[1 + t]);
    }
  }
  // qk tile: o = qr*16 + l15; q (o<32, scaled by log2e) or k. Fragment-linear stores.
  {
    int o = qr * 16 + l15;
    float bias = (o < 32) ? bq[o] : bk[o - 32];
    float scale = (o < 32) ? 1.44269504088896340736f : 1.0f;
    unsigned short* dst = (o < 32) ? qbf : kbf;
    int oc = o & 31;
    int kh = oc >> 4, h2 = (oc >> 3) & 1, c8 = oc & 7;
#pragma unroll
    for (int r = 0; r < 4; ++r) {
      int m = m0 + quad * 4 + r;
      dst[(size_t)b * 131072 + (size_t)(m >> 5) * 1024 + kh * 512 + h2 * 256 +
          (m & 31) * 8 + c8] = f2bf((acc[0][r] + bias) * scale);
    }
  }
  // v tiles (4 -> 64 channels): per-wave LDS transpose then fragment-linear stores
#pragma unroll
  for (int t = 0; t < 4; ++t) {
    int lr = t * 16 + l15;                  // local channel 0..63
    int c = qr * 64 + lr;                   // global v channel
    float bias = bv[c];
#pragma unroll
    for (int r = 0; r < 4; ++r)
      Os[qr][lr][quad * 4 + r] = f2bf(acc[1 + t][r] + bias);
  }
  // Os[qr] is produced and consumed by this wave only -> in-order within the wave.
  {
    int kb = nt >> 1, kk = nt & 1;          // this tile = one kk-half of key-block kb
#pragma unroll
    for (int i = 0; i < 2; ++i) {
      int idx = lane + 64 * i;              // 128 granules of 16B per wave
      int r = idx >> 1, g = idx & 1;        // r = local ch 0..63, g = hi half
      int c = qr * 64 + r;
      int cb = c >> 5, ch = c & 31;
      *(uint4*)(vbf + (size_t)b * 1048576 + (size_t)kb * 8192 +
                (size_t)cb * 1024 + kk * 512 + g * 256 + ch * 8) =
          *(const uint4*)&Os[qr][r][g * 8];
    }
  }
}

// ---------- softmax helper (unchanged, verified) ----------
__device__ __forceinline__ void softmax_pack(floatx16 st, float& lp, bf16x8 (&pa)[2], int hi) {
  float p[16];
#pragma unroll
  for (int r = 0; r < 16; ++r) p[r] = exp2_fast(st[r]);
  lp += (((p[0] + p[1]) + (p[2] + p[3])) + ((p[4] + p[5]) + (p[6] + p[7]))) +
        (((p[8] + p[9]) + (p[10] + p[11])) + ((p[12] + p[13]) + (p[14] + p[15])));
  unsigned d0[4], d1[4];
#pragma unroll
  for (int t = 0; t < 4; ++t) {
    d0[t] = pack2(p[4 * t + 0], p[4 * t + 1]);
    d1[t] = pack2(p[4 * t + 2], p[4 * t + 3]);
  }
#pragma unroll
  for (int ks = 0; ks < 2; ++ks) {
#if __has_builtin(__builtin_amdgcn_permlane32_swap)
    (void)hi;
    u32x2 r0 = __builtin_amdgcn_permlane32_swap(d0[2 * ks], d0[2 * ks + 1], false, false);
    u32x2 r1 = __builtin_amdgcn_permlane32_swap(d1[2 * ks], d1[2 * ks + 1], false, false);
    union { unsigned u[4]; bf16x8 v; } u;
    u.u[0] = r0[0]; u.u[1] = r1[0]; u.u[2] = r0[1]; u.u[3] = r1[1];
    pa[ks] = u.v;
#else
    unsigned s0 = hi ? d0[2 * ks] : d0[2 * ks + 1];
    unsigned s1 = hi ? d1[2 * ks] : d1[2 * ks + 1];
    unsigned o0 = (unsigned)__shfl_xor((int)s0, 32);
    unsigned o1 = (unsigned)__shfl_xor((int)s1, 32);
    union { unsigned u[4]; bf16x8 v; } u;
    u.u[0] = hi ? o0 : d0[2 * ks];
    u.u[1] = hi ? o1 : d1[2 * ks];
    u.u[2] = hi ? d0[2 * ks + 1] : o0;
    u.u[3] = hi ? d1[2 * ks + 1] : o1;
    pa[ks] = u.v;
#endif
  }
}

// ---------- K_attn v9 (round-12/14 best, verbatim): 4-wave blocks + fused merge ----------
// Main loop per wave = v5 (64q x 128ch, barrier-free, in-register softmax).
// Block = (b, cw, qb) with 4 waves, one per key-split s; LDS epilogue reduces the
// 4 splits' (O_s, l_s) in-block and writes out = x + gamma * sumO / suml directly.
// grid = 512 = b(4) x cw(2) x qb(64); XCD-swizzled: XCD x owns one (b,cw) V-set (1MB).
__global__ __launch_bounds__(256, 2) void k_attn(const unsigned short* __restrict__ qbf,
                                                 const unsigned short* __restrict__ kbf,
                                                 const unsigned short* __restrict__ vbf,
                                                 const float* __restrict__ x,
                                                 const float* __restrict__ gma,
                                                 float* __restrict__ out) {
  // XCD swizzle: nwg=512, 8 XCDs -> XCD x owns decoded range [x*64, x*64+64)
  int wg = (blockIdx.x & 7) * 64 + (blockIdx.x >> 3);
  const int qb = wg & 63;
  const int g  = wg >> 6;
  const int cw = g & 1;
  const int b  = g >> 1;
  const int s  = threadIdx.x >> 6;          // wave id = key-split
  const int lane = threadIdx.x & 63;
  const int l31 = lane & 31;
  const int hi  = lane >> 5;
  const int q0  = qb * 64;

  __shared__ float lpL[4][64];
  __shared__ float ltot[64];
  __shared__ alignas(16) unsigned short Ol[4][128][40];   // padded rows (80B) for banks

  const floatx16 z16 = {0.f, 0.f, 0.f, 0.f, 0.f, 0.f, 0.f, 0.f,
                        0.f, 0.f, 0.f, 0.f, 0.f, 0.f, 0.f, 0.f};

  // Q fragments (B-operand: col = query l31, row ch = kh*16 + hi*8 + j), hoisted.
  bf16x8 qf[2][2];
  {
    const unsigned short* qbase =
        qbf + (size_t)b * 131072 + (size_t)(qb * 2) * 1024 + hi * 256 + l31 * 8;
#pragma unroll
    for (int qs2 = 0; qs2 < 2; ++qs2)
#pragma unroll
      for (int kh = 0; kh < 2; ++kh)
        qf[qs2][kh] = *(const bf16x8*)(qbase + qs2 * 1024 + kh * 512);
  }

  floatx16 acc[2][4];
#pragma unroll
  for (int i = 0; i < 2; ++i)
#pragma unroll
    for (int j = 0; j < 4; ++j) acc[i][j] = z16;

  float lp0 = 0.f, lp1 = 0.f;

  // K fragment base (A-operand: row = key l31, ch = kh*16 + hi*8 + j)
  const unsigned short* krow =
      kbf + (size_t)b * 131072 + (size_t)(s * 32) * 1024 + hi * 256 + l31 * 8;
  // V fragment base (B-operand: col = channel l31, key = kk*16 + hi*8 + j)
  const unsigned short* vrow =
      vbf + (size_t)b * 1048576 + (size_t)(s * 32) * 8192 + (size_t)(cw * 4) * 1024 +
      hi * 256 + l31 * 8;

  // ---- prologue: ST(0), then load K(1) into the single K buffer ----
  bf16x8 kf0 = *(const bf16x8*)krow;
  bf16x8 kf1 = *(const bf16x8*)(krow + 512);
  floatx16 st0 = MFMA32(kf0, qf[0][0], z16);
  st0 = MFMA32(kf1, qf[0][1], st0);
  floatx16 st1 = MFMA32(kf0, qf[1][0], z16);
  st1 = MFMA32(kf1, qf[1][1], st1);
  kf0 = *(const bf16x8*)(krow + 1024);
  kf1 = *(const bf16x8*)(krow + 1024 + 512);

  for (int it = 0; it < 32; ++it) {
    // ---- V loads first: consumed at PV (softmax + ST issue in between)
    bf16x8 vb[4][2];
    const unsigned short* vit = vrow + (size_t)it * 8192;
#pragma unroll
    for (int ct = 0; ct < 4; ++ct) {
      vb[ct][0] = *(const bf16x8*)(vit + ct * 1024);
      vb[ct][1] = *(const bf16x8*)(vit + ct * 1024 + 512);
    }

    // ---- softmax on st = S^T(it), computed LAST iteration -> no wait ----
    bf16x8 pa[2][2];
    softmax_pack(st0, lp0, pa[0], hi);
    softmax_pack(st1, lp1, pa[1], hi);

    // ---- ST(it+1): reuses st regs; kf holds K(it+1). Wrapped last iter -> dead compute.
    st0 = MFMA32(kf0, qf[0][0], z16);
    st0 = MFMA32(kf1, qf[0][1], st0);
    st1 = MFMA32(kf0, qf[1][0], z16);
    st1 = MFMA32(kf1, qf[1][1], st1);

    // ---- K(it+2) load (consumed next iter's ST; wrapped index in-region) ----
    const unsigned short* kn = krow + (size_t)((it + 2) & 31) * 1024;
    kf0 = *(const bf16x8*)kn;
    kf1 = *(const bf16x8*)(kn + 512);

    // ---- PV(it): 16 MFMAs, V frags reused across both query subtiles ----
    __builtin_amdgcn_s_setprio(1);
#pragma unroll
    for (int ct = 0; ct < 4; ++ct) {
      acc[0][ct] = MFMA32(pa[0][0], vb[ct][0], acc[0][ct]);
      acc[1][ct] = MFMA32(pa[1][0], vb[ct][0], acc[1][ct]);
      acc[0][ct] = MFMA32(pa[0][1], vb[ct][1], acc[0][ct]);
      acc[1][ct] = MFMA32(pa[1][1], vb[ct][1], acc[1][ct]);
    }
    __builtin_amdgcn_s_setprio(0);
  }

  // ---- fused cross-split reduction + normalize + residual epilogue ----
  lp0 += __shfl_xor(lp0, 32);
  lp1 += __shfl_xor(lp1, 32);
  lpL[s][hi * 32 + l31] = hi ? lp1 : lp0;   // query q0 + hi*32 + l31
  __syncthreads();
  if (threadIdx.x < 64) {
    int q = threadIdx.x;
    ltot[q] = (lpL[0][q] + lpL[1][q]) + (lpL[2][q] + lpL[3][q]);
  }
  const float gv = gma[0];

#pragma unroll
  for (int qs2 = 0; qs2 < 2; ++qs2) {
    // write this wave's 32q x 128ch partial O (bf16, RNE - same rounding as old Obf)
#pragma unroll
    for (int ct = 0; ct < 4; ++ct) {
#pragma unroll
      for (int gi = 0; gi < 4; ++gi) {
        unsigned w0 = pack2(acc[qs2][ct][4 * gi + 0], acc[qs2][ct][4 * gi + 1]);
        unsigned w1 = pack2(acc[qs2][ct][4 * gi + 2], acc[qs2][ct][4 * gi + 3]);
        unsigned long long w = (unsigned long long)w0 | ((unsigned long long)w1 << 32);
        *(unsigned long long*)&Ol[s][ct * 32 + l31][8 * gi + 4 * hi] = w;
      }
    }
    __syncthreads();   // Ol (and, first pass, ltot) ready
    {
      int ch = threadIdx.x >> 1;            // 0..127
      int qh = threadIdx.x & 1;             // 16-query half
      int qoff = qs2 * 32 + qh * 16;
      float o[16];
#pragma unroll
      for (int j = 0; j < 16; ++j) o[j] = 0.f;
#pragma unroll
      for (int sp = 0; sp < 4; ++sp) {
        const uint4* p = (const uint4*)&Ol[sp][ch][qh * 16];
        uint4 a0 = p[0], a1 = p[1];
        unsigned uu[8] = {a0.x, a0.y, a0.z, a0.w, a1.x, a1.y, a1.z, a1.w};
#pragma unroll
        for (int jj = 0; jj < 8; ++jj) {
          o[2 * jj + 0] += bf2f((unsigned short)(uu[jj] & 0xffffu));
          o[2 * jj + 1] += bf2f((unsigned short)(uu[jj] >> 16));
        }
      }
      size_t rowa = ((size_t)b * 256 + cw * 128 + ch) * 4096 + q0 + qoff;
      const float* xrow = x + rowa;
      float* orow = out + rowa;
#pragma unroll
      for (int j4 = 0; j4 < 4; ++j4) {
        float4 xv = *(const float4*)(xrow + j4 * 4);
        float4 r;
        r.x = xv.x + gv * o[j4 * 4 + 0] / ltot[qoff + j4 * 4 + 0];
        r.y = xv.y + gv * o[j4 * 4 + 1] / ltot[qoff + j4 * 4 + 1];
        r.z = xv.z + gv * o[j4 * 4 + 2] / ltot[qoff + j4 * 4 + 2];
        r.w = xv.w + gv * o[j4 * 4 + 3] / ltot[qoff + j4 * 4 + 3];
        *(float4*)(orow + j4 * 4) = r;
      }
    }
    __syncthreads();   // drain readers before next phase overwrites Ol
  }
}

// ---------- launch ----------
extern "C" void kernel_launch(void* const* d_in, const int* in_sizes, int n_in,
                              void* d_out, int out_size, void* d_ws, size_t ws_size,
                              hipStream_t stream) {
  const float* x   = (const float*)d_in[0];
  const float* Wq  = (const float*)d_in[1];
  const float* bq  = (const float*)d_in[2];
  const float* Wk  = (const float*)d_in[3];
  const float* bk  = (const float*)d_in[4];
  const float* Wv  = (const float*)d_in[5];
  const float* bv  = (const float*)d_in[6];
  const float* gma = (const float*)d_in[7];
  float* out = (float*)d_out;

  // layout: [qbf][kbf][vbf][Wall]
  unsigned short* qbf  = (unsigned short*)d_ws;              // [4][128][2][2][32][8]
  unsigned short* kbf  = qbf + (size_t)4 * 131072;           // [4][128][2][2][32][8]
  unsigned short* vbf  = kbf + (size_t)4 * 131072;           // [4][128][8][2][2][32][8]
  unsigned short* Wall = vbf + (size_t)4 * 1048576;          // [320][256]

  k_wconv<<<320, 256, 0, stream>>>(Wq, Wk, Wv, Wall);
  k_projx<<<1024, 256, 0, stream>>>(x, Wall, bq, bk, bv, qbf, kbf, vbf);
  k_attn<<<512, 256, 0, stream>>>(qbf, kbf, vbf, x, gma, out);
}